// Round 14
// baseline (7676.823 us; speedup 1.0000x reference)
//
#include <hip/hip_runtime.h>

// voltageNN: 2-layer LSTM (H=256, P=1, in=1), T=1000, B=16384, + MLP head.
// Round-13: R11 base (best, 6.15ms: batch-packed v2f, in-kernel head, LDS
// h1buf) with the cell restructured into explicit STAGES so the 40 exp2 per
// layer-call issue back-to-back (trans-pipe streaming instead of paying
// trans->VALU interlock per op), plus QUAD-merged rcp (8 rcp/iter, was 16).
// Math identical in exact arithmetic to R6/R11 (both passed absmax 0.0):
//   sigma(z)=1/(1+I), I=2^(-L2E z); tanh(z)=(G-1)/(G+1), G=2^(2 L2E z)
//   cn_k = [u_k*c_k + (G_k-1)(1+F_k)] / D_k,  D_k=(1+F_k)(G_k+1)(I_k+1)
//     computed as num_k * prod_{j!=k} D_j * rcp(prod_j D_j)   [quad merge]
//   o*tanh(cn) = (E-1) / [(E+1)(1+O)], E=2^(2 L2E cn)        [quad merge]
// Ranges: |c|<=~5.3 -> E<=2^15.3; D<=562, D^4<=1e11; d<=9e4, d^4<=6e19 - safe.

#define T_LEN 1000
#define WAVES 4     // waves per block
#define BPW   2     // batch elements per wave (packed into v2f halves)
#define L2E 1.44269504088896340736f

typedef float v2f __attribute__((ext_vector_type(2)));

static __device__ __forceinline__ float exp2r(float x) { return __builtin_amdgcn_exp2f(x); }
static __device__ __forceinline__ float rcpr (float x) { return __builtin_amdgcn_rcpf(x); }
static __device__ __forceinline__ v2f fma2(v2f a, v2f b, v2f c) {
    return __builtin_elementwise_fma(a, b, c);
}
static __device__ __forceinline__ v2f splat2(float s) { v2f r; r.x = s; r.y = s; return r; }

template<int CTRL>
static __device__ __forceinline__ float dpp0(float x) {
    return __int_as_float(__builtin_amdgcn_update_dpp(
        0, __float_as_int(x), CTRL, 0xf, 0xf, true));
}
// sum across 64 lanes; result valid in lane 63
static __device__ __forceinline__ float wave_sum63(float x) {
    x += dpp0<0x111>(x);   // row_shr:1
    x += dpp0<0x112>(x);   // row_shr:2
    x += dpp0<0x114>(x);   // row_shr:4
    x += dpp0<0x118>(x);   // row_shr:8
    x += dpp0<0x142>(x);   // row_bcast:15
    x += dpp0<0x143>(x);   // row_bcast:31
    return x;
}
static __device__ __forceinline__ float lane63(float x) {
    return __int_as_float(__builtin_amdgcn_readlane(__float_as_int(x), 63));
}
static __device__ __forceinline__ float rdlane(float x, int l) {
    return __int_as_float(__builtin_amdgcn_readlane(__float_as_int(x), l));
}

struct CellW {                          // scalar weights, 52 VGPRs/layer
    float wi[4], wf[4], wg[4], wo[4];   // input weights (prescaled)
    float vi[4], vf[4], vg[4], vo[4];   // recurrent weights (prescaled)
    float bi[4], bf[4], bg[4], bo[4];   // biases (bih+bhh, prescaled)
    float wr[4];                        // projection row
};

static __device__ __forceinline__ void load_w(CellW& W, int lane,
        const float* __restrict__ Wih, const float* __restrict__ Whh,
        const float* __restrict__ bih, const float* __restrict__ bhh,
        const float* __restrict__ Whr) {
#pragma unroll
    for (int k = 0; k < 4; ++k) {
        int u = lane + 64 * k;
        W.wi[k] = -L2E * Wih[u];
        W.wf[k] = -L2E * Wih[256 + u];
        W.wg[k] = 2.0f * L2E * Wih[512 + u];
        W.wo[k] = -L2E * Wih[768 + u];
        W.vi[k] = -L2E * Whh[u];
        W.vf[k] = -L2E * Whh[256 + u];
        W.vg[k] = 2.0f * L2E * Whh[512 + u];
        W.vo[k] = -L2E * Whh[768 + u];
        W.bi[k] = -L2E * (bih[u] + bhh[u]);
        W.bf[k] = -L2E * (bih[256 + u] + bhh[256 + u]);
        W.bg[k] = 2.0f * L2E * (bih[512 + u] + bhh[512 + u]);
        W.bo[k] = -L2E * (bih[768 + u] + bhh[768 + u]);
        W.wr[k] = Whr[u];
    }
}

// One LSTM cell step, STAGED: 4 units x both batches (v2f halves).
static __device__ __forceinline__ v2f cell2(const CellW& W, v2f xt, v2f h,
                                            v2f (&c)[4], v2f k2) {
    // --- stage 1: all 32 gate FMAs ---
    v2f yi[4], yf[4], yg[4], yo[4];
#pragma unroll
    for (int k = 0; k < 4; ++k) {
        yi[k] = fma2(xt, splat2(W.wi[k]), fma2(h, splat2(W.vi[k]), splat2(W.bi[k])));
        yf[k] = fma2(xt, splat2(W.wf[k]), fma2(h, splat2(W.vf[k]), splat2(W.bf[k])));
        yg[k] = fma2(xt, splat2(W.wg[k]), fma2(h, splat2(W.vg[k]), splat2(W.bg[k])));
        yo[k] = fma2(xt, splat2(W.wo[k]), fma2(h, splat2(W.vo[k]), splat2(W.bo[k])));
    }
    // --- stage 2: 32 exp2, back-to-back (trans-pipe streaming) ---
    v2f I[4], F[4], G[4], O[4];
#pragma unroll
    for (int k = 0; k < 4; ++k) {
        I[k].x = exp2r(yi[k].x); I[k].y = exp2r(yi[k].y);
        F[k].x = exp2r(yf[k].x); F[k].y = exp2r(yf[k].y);
        G[k].x = exp2r(yg[k].x); G[k].y = exp2r(yg[k].y);
        O[k].x = exp2r(yo[k].x); O[k].y = exp2r(yo[k].y);
    }
    // --- stage 3: per-k denominator & numerator ---
    v2f D[4], num[4];
#pragma unroll
    for (int k = 0; k < 4; ++k) {
        v2f w1 = F[k] + 1.0f;
        v2f u  = (G[k] + 1.0f) * (I[k] + 1.0f);
        num[k] = fma2(u, c[k], (G[k] - 1.0f) * w1);
        D[k]   = w1 * u;
    }
    // --- stage 4: quad-merged rcp, cn ---
    v2f P01 = D[0] * D[1];
    v2f P23 = D[2] * D[3];
    v2f Dall = P01 * P23;
    v2f r;
    r.x = rcpr(Dall.x); r.y = rcpr(Dall.y);
    v2f od0 = D[1] * P23, od1 = D[0] * P23, od2 = D[3] * P01, od3 = D[2] * P01;
    v2f cn[4];
    cn[0] = (num[0] * od0) * r;
    cn[1] = (num[1] * od1) * r;
    cn[2] = (num[2] * od2) * r;
    cn[3] = (num[3] * od3) * r;
#pragma unroll
    for (int k = 0; k < 4; ++k) c[k] = cn[k];
    // --- stage 5: 8 exp2, back-to-back ---
    v2f E[4];
#pragma unroll
    for (int k = 0; k < 4; ++k) {
        v2f yE = cn[k] * k2;
        E[k].x = exp2r(yE.x); E[k].y = exp2r(yE.y);
    }
    // --- stage 6: d, q, quad-merged rcp, s ---
    v2f d[4], q[4];
#pragma unroll
    for (int k = 0; k < 4; ++k) {
        d[k] = (E[k] + 1.0f) * (O[k] + 1.0f);
        q[k] = (E[k] - 1.0f) * splat2(W.wr[k]);
    }
    v2f Q01 = d[0] * d[1];
    v2f Q23 = d[2] * d[3];
    v2f dall = Q01 * Q23;
    v2f r2;
    r2.x = rcpr(dall.x); r2.y = rcpr(dall.y);
    v2f t0 = q[0] * (d[1] * Q23);
    v2f t1 = q[1] * (d[0] * Q23);
    v2f t2 = q[2] * (d[3] * Q01);
    v2f t3 = q[3] * (d[2] * Q01);
    return ((t0 + t1) + (t2 + t3)) * r2;
}

__global__ __launch_bounds__(256, 1)
void voltage_lstm_kernel(const float* __restrict__ x,
        const float* __restrict__ Wih0, const float* __restrict__ Whh0,
        const float* __restrict__ bih0, const float* __restrict__ bhh0,
        const float* __restrict__ Whr0,
        const float* __restrict__ Wih1, const float* __restrict__ Whh1,
        const float* __restrict__ bih1, const float* __restrict__ bhh1,
        const float* __restrict__ Whr1,
        const float* __restrict__ W1, const float* __restrict__ b1p,
        const float* __restrict__ W2, const float* __restrict__ b2,
        float* __restrict__ out)
{
    __shared__ __align__(16) float h1buf[WAVES][BPW][T_LEN];

    const int lane = threadIdx.x & 63;
    const int wv   = threadIdx.x >> 6;
    const int w    = blockIdx.x * WAVES + wv;
    const int bA   = w * BPW;
    const int bB   = bA + 1;

    CellW W0c, W1c;
    load_w(W0c, lane, Wih0, Whh0, bih0, bhh0, Whr0);
    load_w(W1c, lane, Wih1, Whh1, bih1, bhh1, Whr1);

    const v2f k2 = splat2(2.0f * L2E);

    v2f c0[4], c1[4];
#pragma unroll
    for (int k = 0; k < 4; ++k) { c0[k] = splat2(0.f); c1[k] = splat2(0.f); }

    const float* xA = x + (long)bA * T_LEN;
    const float* xB = x + (long)bB * T_LEN;
    float xcA = xA[lane];              // x chunk for t in [0,64)
    float xcB = xB[lane];

    // --- prologue: layer0 step 0 (h0=0) ---
    v2f h0, h1;
    {
        v2f xt0;
        xt0.x = rdlane(xcA, 0);
        xt0.y = rdlane(xcB, 0);
        v2f a = cell2(W0c, xt0, splat2(0.0f), c0, k2);
        h0.x = lane63(wave_sum63(a.x));
        h0.y = lane63(wave_sum63(a.y));
        h1 = splat2(0.0f);
    }

    // --- main loop: iter j computes layer0 step j+1 AND layer1 step j ---
    for (int j = 0; j < T_LEN - 1; ++j) {
        const int idx = j + 1;
        if ((idx & 63) == 0) {
            int tl = idx + lane;
            xcA = (tl < T_LEN) ? xA[tl] : 0.0f;
            xcB = (tl < T_LEN) ? xB[tl] : 0.0f;
        }
        v2f xt;
        xt.x = rdlane(xcA, idx & 63);
        xt.y = rdlane(xcB, idx & 63);

        v2f a0 = cell2(W0c, xt, h0, c0, k2);   // layer0, step idx
        v2f a1 = cell2(W1c, h0, h1, c1, k2);   // layer1, step j

        float r0x = wave_sum63(a0.x);
        float r0y = wave_sum63(a0.y);
        float r1x = wave_sum63(a1.x);
        float r1y = wave_sum63(a1.y);

        if (lane == 63) {
            h1buf[wv][0][j] = r1x;
            h1buf[wv][1][j] = r1y;
        }
        h0.x = lane63(r0x);  h0.y = lane63(r0y);
        h1.x = lane63(r1x);  h1.y = lane63(r1y);
    }
    // --- epilogue: layer1 step T-1 ---
    {
        v2f a1 = cell2(W1c, h0, h1, c1, k2);
        float r1x = wave_sum63(a1.x);
        float r1y = wave_sum63(a1.y);
        if (lane == 63) {
            h1buf[wv][0][T_LEN - 1] = r1x;
            h1buf[wv][1][T_LEN - 1] = r1y;
        }
    }
    __syncthreads();

    // --- head: relu(h1 @ W1^T + b1) @ W2^T + b2 for both batches ---
    const float* hA = h1buf[wv][0];
    const float* hB = h1buf[wv][1];
    const int j0 = lane;                 // rows 0..63
    const int j1 = lane + 64;            // rows 64..99 (lanes 0..35)
    const bool has1 = (j1 < 100);
    const float* r0 = W1 + j0 * T_LEN;
    const float* r1 = W1 + (has1 ? j1 : 0) * T_LEN;
    float aA0 = 0.f, aA1 = 0.f, aB0 = 0.f, aB1 = 0.f;
    for (int t = 0; t < T_LEN; t += 4) {
        float4 u0 = *(const float4*)(r0 + t);
        float4 u1 = *(const float4*)(r1 + t);
        float4 pA = *(const float4*)(hA + t);
        float4 pB = *(const float4*)(hB + t);
        aA0 = fmaf(u0.x, pA.x, aA0); aA0 = fmaf(u0.y, pA.y, aA0);
        aA0 = fmaf(u0.z, pA.z, aA0); aA0 = fmaf(u0.w, pA.w, aA0);
        aA1 = fmaf(u1.x, pA.x, aA1); aA1 = fmaf(u1.y, pA.y, aA1);
        aA1 = fmaf(u1.z, pA.z, aA1); aA1 = fmaf(u1.w, pA.w, aA1);
        aB0 = fmaf(u0.x, pB.x, aB0); aB0 = fmaf(u0.y, pB.y, aB0);
        aB0 = fmaf(u0.z, pB.z, aB0); aB0 = fmaf(u0.w, pB.w, aB0);
        aB1 = fmaf(u1.x, pB.x, aB1); aB1 = fmaf(u1.y, pB.y, aB1);
        aB1 = fmaf(u1.z, pB.z, aB1); aB1 = fmaf(u1.w, pB.w, aB1);
    }
    float bb0 = b1p[j0],   w20 = W2[j0];
    float bb1 = has1 ? b1p[j1] : 0.f;
    float w21 = has1 ? W2[j1]  : 0.f;
    float sA = fmaxf(aA0 + bb0, 0.f) * w20;
    float sB = fmaxf(aB0 + bb0, 0.f) * w20;
    if (has1) {
        sA = fmaf(fmaxf(aA1 + bb1, 0.f), w21, sA);
        sB = fmaf(fmaxf(aB1 + bb1, 0.f), w21, sB);
    }
    sA = wave_sum63(sA);
    sB = wave_sum63(sB);
    if (lane == 63) {
        float bias2 = b2[0];
        out[bA] = sA + bias2;
        out[bB] = sB + bias2;
    }
}

extern "C" void kernel_launch(void* const* d_in, const int* in_sizes, int n_in,
                              void* d_out, int out_size, void* d_ws, size_t ws_size,
                              hipStream_t stream) {
    (void)in_sizes; (void)n_in; (void)d_ws; (void)ws_size; (void)out_size;
    const float* x    = (const float*)d_in[0];
    const float* Wih0 = (const float*)d_in[1];
    const float* Whh0 = (const float*)d_in[2];
    const float* bih0 = (const float*)d_in[3];
    const float* bhh0 = (const float*)d_in[4];
    const float* Whr0 = (const float*)d_in[5];
    const float* Wih1 = (const float*)d_in[6];
    const float* Whh1 = (const float*)d_in[7];
    const float* bih1 = (const float*)d_in[8];
    const float* bhh1 = (const float*)d_in[9];
    const float* Whr1 = (const float*)d_in[10];
    const float* W1   = (const float*)d_in[11];
    const float* b1   = (const float*)d_in[12];
    const float* W2   = (const float*)d_in[13];
    const float* b2   = (const float*)d_in[14];
    float* outp = (float*)d_out;

    dim3 grid(16384 / (WAVES * BPW)), block(64 * WAVES);
    voltage_lstm_kernel<<<grid, block, 0, stream>>>(
        x, Wih0, Whh0, bih0, bhh0, Whr0,
        Wih1, Whh1, bih1, bhh1, Whr1,
        W1, b1, W2, b2, outp);
}

// Round 15
// 6144.236 us; speedup vs baseline: 1.2494x; 1.2494x over previous
//
#include <hip/hip_runtime.h>

// voltageNN: 2-layer LSTM (H=256, P=1, in=1), T=1000, B=16384, + MLP head.
// FINAL (R11, best measured 6.15ms): batch-packed v2f pk math, in-kernel head.
// - One wave per 2 batch elements; lane owns units u = lane + 64k (k=0..3)
//   for both layers; v2f halves = the 2 BATCHES (zero swap glue; weights
//   scalar, splat at use folds to VOP3P op_sel).
// - Recurrent scalars via readlane; reductions via builtin update_dpp tree
//   (compiler inserts DPP hazard nops; raw asm DPP raced in R7).
// - Trans budget (algorithmic floor): 5 exp2/unit-step + pair-merged rcp
//   (80 exp2 + 16 rcp per wave-iter):
//     sigma(z)=1/(1+I), I=2^(-L2E z); tanh(z)=(G-1)/(G+1), G=2^(2 L2E z)
//     cn = [u*c + (G-1)(1+F)] / [(1+F)*u],  u=(G+1)(1+I)
//     o*tanh(cn) = (E-1) / [(E+1)(1+O)],    E=2^(2 L2E cn) (|c|<=~4.4, safe)
// - VGPR=128 is exactly the 4-wave/SIMD boundary: ANY register growth drops
//   a wave and nets negative (R13: +8 VGPR -> -25% perf). Do not add live
//   ranges. VALUBusy ~95% = VALU/trans port saturated; compute roofline.

#define T_LEN 1000
#define WAVES 4     // waves per block
#define BPW   2     // batch elements per wave (packed into v2f halves)
#define L2E 1.44269504088896340736f

typedef float v2f __attribute__((ext_vector_type(2)));

static __device__ __forceinline__ float exp2r(float x) { return __builtin_amdgcn_exp2f(x); }
static __device__ __forceinline__ float rcpr (float x) { return __builtin_amdgcn_rcpf(x); }
static __device__ __forceinline__ v2f fma2(v2f a, v2f b, v2f c) {
    return __builtin_elementwise_fma(a, b, c);
}
static __device__ __forceinline__ v2f splat2(float s) { v2f r; r.x = s; r.y = s; return r; }

template<int CTRL>
static __device__ __forceinline__ float dpp0(float x) {
    return __int_as_float(__builtin_amdgcn_update_dpp(
        0, __float_as_int(x), CTRL, 0xf, 0xf, true));
}
// sum across 64 lanes; result valid in lane 63
static __device__ __forceinline__ float wave_sum63(float x) {
    x += dpp0<0x111>(x);   // row_shr:1
    x += dpp0<0x112>(x);   // row_shr:2
    x += dpp0<0x114>(x);   // row_shr:4
    x += dpp0<0x118>(x);   // row_shr:8
    x += dpp0<0x142>(x);   // row_bcast:15
    x += dpp0<0x143>(x);   // row_bcast:31
    return x;
}
static __device__ __forceinline__ float lane63(float x) {
    return __int_as_float(__builtin_amdgcn_readlane(__float_as_int(x), 63));
}
static __device__ __forceinline__ float rdlane(float x, int l) {
    return __int_as_float(__builtin_amdgcn_readlane(__float_as_int(x), l));
}

struct CellW {                          // scalar weights, 52 VGPRs/layer
    float wi[4], wf[4], wg[4], wo[4];   // input weights (prescaled)
    float vi[4], vf[4], vg[4], vo[4];   // recurrent weights (prescaled)
    float bi[4], bf[4], bg[4], bo[4];   // biases (bih+bhh, prescaled)
    float wr[4];                        // projection row
};

static __device__ __forceinline__ void load_w(CellW& W, int lane,
        const float* __restrict__ Wih, const float* __restrict__ Whh,
        const float* __restrict__ bih, const float* __restrict__ bhh,
        const float* __restrict__ Whr) {
#pragma unroll
    for (int k = 0; k < 4; ++k) {
        int u = lane + 64 * k;
        W.wi[k] = -L2E * Wih[u];
        W.wf[k] = -L2E * Wih[256 + u];
        W.wg[k] = 2.0f * L2E * Wih[512 + u];
        W.wo[k] = -L2E * Wih[768 + u];
        W.vi[k] = -L2E * Whh[u];
        W.vf[k] = -L2E * Whh[256 + u];
        W.vg[k] = 2.0f * L2E * Whh[512 + u];
        W.vo[k] = -L2E * Whh[768 + u];
        W.bi[k] = -L2E * (bih[u] + bhh[u]);
        W.bf[k] = -L2E * (bih[256 + u] + bhh[256 + u]);
        W.bg[k] = 2.0f * L2E * (bih[512 + u] + bhh[512 + u]);
        W.bo[k] = -L2E * (bih[768 + u] + bhh[768 + u]);
        W.wr[k] = Whr[u];
    }
}

// One LSTM cell step for this lane's 4 units x BOTH batches (v2f halves).
static __device__ __forceinline__ v2f cell2(const CellW& W, v2f xt, v2f h,
                                            v2f (&c)[4], v2f k2) {
    v2f s = splat2(0.0f);
#pragma unroll
    for (int p = 0; p < 2; ++p) {
        const int k0 = 2 * p, k1 = 2 * p + 1;
        v2f yi0 = fma2(xt, splat2(W.wi[k0]), fma2(h, splat2(W.vi[k0]), splat2(W.bi[k0])));
        v2f yf0 = fma2(xt, splat2(W.wf[k0]), fma2(h, splat2(W.vf[k0]), splat2(W.bf[k0])));
        v2f yg0 = fma2(xt, splat2(W.wg[k0]), fma2(h, splat2(W.vg[k0]), splat2(W.bg[k0])));
        v2f yo0 = fma2(xt, splat2(W.wo[k0]), fma2(h, splat2(W.vo[k0]), splat2(W.bo[k0])));
        v2f yi1 = fma2(xt, splat2(W.wi[k1]), fma2(h, splat2(W.vi[k1]), splat2(W.bi[k1])));
        v2f yf1 = fma2(xt, splat2(W.wf[k1]), fma2(h, splat2(W.vf[k1]), splat2(W.bf[k1])));
        v2f yg1 = fma2(xt, splat2(W.wg[k1]), fma2(h, splat2(W.vg[k1]), splat2(W.bg[k1])));
        v2f yo1 = fma2(xt, splat2(W.wo[k1]), fma2(h, splat2(W.vo[k1]), splat2(W.bo[k1])));

        v2f I0, F0, G0, O0, I1, F1, G1, O1;
        I0.x = exp2r(yi0.x); I0.y = exp2r(yi0.y);
        F0.x = exp2r(yf0.x); F0.y = exp2r(yf0.y);
        G0.x = exp2r(yg0.x); G0.y = exp2r(yg0.y);
        O0.x = exp2r(yo0.x); O0.y = exp2r(yo0.y);
        I1.x = exp2r(yi1.x); I1.y = exp2r(yi1.y);
        F1.x = exp2r(yf1.x); F1.y = exp2r(yf1.y);
        G1.x = exp2r(yg1.x); G1.y = exp2r(yg1.y);
        O1.x = exp2r(yo1.x); O1.y = exp2r(yo1.y);

        v2f w10 = F0 + 1.0f;
        v2f w11 = F1 + 1.0f;
        v2f u0  = (G0 + 1.0f) * (I0 + 1.0f);
        v2f u1  = (G1 + 1.0f) * (I1 + 1.0f);
        v2f num0 = fma2(u0, c[k0], (G0 - 1.0f) * w10);
        v2f num1 = fma2(u1, c[k1], (G1 - 1.0f) * w11);
        v2f D0 = w10 * u0;
        v2f D1 = w11 * u1;
        v2f Dp = D0 * D1;                 // per-half product across k-pair
        v2f rP;
        rP.x = rcpr(Dp.x); rP.y = rcpr(Dp.y);
        v2f cn0 = (num0 * D1) * rP;       // no swap: cross term is D1 (other k)
        v2f cn1 = (num1 * D0) * rP;
        c[k0] = cn0;
        c[k1] = cn1;

        v2f yE0 = cn0 * k2;               // |c|<=~4.4 -> no overflow
        v2f yE1 = cn1 * k2;
        v2f E0, E1;
        E0.x = exp2r(yE0.x); E0.y = exp2r(yE0.y);
        E1.x = exp2r(yE1.x); E1.y = exp2r(yE1.y);
        v2f d0 = (E0 + 1.0f) * (O0 + 1.0f);
        v2f d1 = (E1 + 1.0f) * (O1 + 1.0f);
        v2f q0 = (E0 - 1.0f) * splat2(W.wr[k0]);
        v2f q1 = (E1 - 1.0f) * splat2(W.wr[k1]);
        v2f dp = d0 * d1;
        v2f rQ;
        rQ.x = rcpr(dp.x); rQ.y = rcpr(dp.y);
        s = fma2(fma2(q1, d0, q0 * d1), rQ, s);
    }
    return s;
}

__global__ __launch_bounds__(256, 1)
void voltage_lstm_kernel(const float* __restrict__ x,
        const float* __restrict__ Wih0, const float* __restrict__ Whh0,
        const float* __restrict__ bih0, const float* __restrict__ bhh0,
        const float* __restrict__ Whr0,
        const float* __restrict__ Wih1, const float* __restrict__ Whh1,
        const float* __restrict__ bih1, const float* __restrict__ bhh1,
        const float* __restrict__ Whr1,
        const float* __restrict__ W1, const float* __restrict__ b1p,
        const float* __restrict__ W2, const float* __restrict__ b2,
        float* __restrict__ out)
{
    __shared__ __align__(16) float h1buf[WAVES][BPW][T_LEN];

    const int lane = threadIdx.x & 63;
    const int wv   = threadIdx.x >> 6;
    const int w    = blockIdx.x * WAVES + wv;
    const int bA   = w * BPW;
    const int bB   = bA + 1;

    CellW W0c, W1c;
    load_w(W0c, lane, Wih0, Whh0, bih0, bhh0, Whr0);
    load_w(W1c, lane, Wih1, Whh1, bih1, bhh1, Whr1);

    const v2f k2 = splat2(2.0f * L2E);

    v2f c0[4], c1[4];
#pragma unroll
    for (int k = 0; k < 4; ++k) { c0[k] = splat2(0.f); c1[k] = splat2(0.f); }

    const float* xA = x + (long)bA * T_LEN;
    const float* xB = x + (long)bB * T_LEN;
    float xcA = xA[lane];              // x chunk for t in [0,64)
    float xcB = xB[lane];

    // --- prologue: layer0 step 0 (h0=0) ---
    v2f h0, h1;
    {
        v2f xt0;
        xt0.x = rdlane(xcA, 0);
        xt0.y = rdlane(xcB, 0);
        v2f a = cell2(W0c, xt0, splat2(0.0f), c0, k2);
        h0.x = lane63(wave_sum63(a.x));
        h0.y = lane63(wave_sum63(a.y));
        h1 = splat2(0.0f);
    }

    // --- main loop: iter j computes layer0 step j+1 AND layer1 step j
    // (2 packed cell calls = 4 independent chains -> ILP).
    for (int j = 0; j < T_LEN - 1; ++j) {
        const int idx = j + 1;
        if ((idx & 63) == 0) {
            int tl = idx + lane;
            xcA = (tl < T_LEN) ? xA[tl] : 0.0f;
            xcB = (tl < T_LEN) ? xB[tl] : 0.0f;
        }
        v2f xt;
        xt.x = rdlane(xcA, idx & 63);
        xt.y = rdlane(xcB, idx & 63);

        v2f a0 = cell2(W0c, xt, h0, c0, k2);   // layer0, step idx
        v2f a1 = cell2(W1c, h0, h1, c1, k2);   // layer1, step j

        float r0x = wave_sum63(a0.x);
        float r0y = wave_sum63(a0.y);
        float r1x = wave_sum63(a1.x);
        float r1y = wave_sum63(a1.y);

        if (lane == 63) {
            h1buf[wv][0][j] = r1x;
            h1buf[wv][1][j] = r1y;
        }
        h0.x = lane63(r0x);  h0.y = lane63(r0y);
        h1.x = lane63(r1x);  h1.y = lane63(r1y);
    }
    // --- epilogue: layer1 step T-1 ---
    {
        v2f a1 = cell2(W1c, h0, h1, c1, k2);
        float r1x = wave_sum63(a1.x);
        float r1y = wave_sum63(a1.y);
        if (lane == 63) {
            h1buf[wv][0][T_LEN - 1] = r1x;
            h1buf[wv][1][T_LEN - 1] = r1y;
        }
    }
    __syncthreads();

    // --- head: relu(h1 @ W1^T + b1) @ W2^T + b2 for both batches ---
    const float* hA = h1buf[wv][0];
    const float* hB = h1buf[wv][1];
    const int j0 = lane;                 // rows 0..63
    const int j1 = lane + 64;            // rows 64..99 (lanes 0..35)
    const bool has1 = (j1 < 100);
    const float* r0 = W1 + j0 * T_LEN;
    const float* r1 = W1 + (has1 ? j1 : 0) * T_LEN;
    float aA0 = 0.f, aA1 = 0.f, aB0 = 0.f, aB1 = 0.f;
    for (int t = 0; t < T_LEN; t += 4) {
        float4 u0 = *(const float4*)(r0 + t);
        float4 u1 = *(const float4*)(r1 + t);
        float4 pA = *(const float4*)(hA + t);
        float4 pB = *(const float4*)(hB + t);
        aA0 = fmaf(u0.x, pA.x, aA0); aA0 = fmaf(u0.y, pA.y, aA0);
        aA0 = fmaf(u0.z, pA.z, aA0); aA0 = fmaf(u0.w, pA.w, aA0);
        aA1 = fmaf(u1.x, pA.x, aA1); aA1 = fmaf(u1.y, pA.y, aA1);
        aA1 = fmaf(u1.z, pA.z, aA1); aA1 = fmaf(u1.w, pA.w, aA1);
        aB0 = fmaf(u0.x, pB.x, aB0); aB0 = fmaf(u0.y, pB.y, aB0);
        aB0 = fmaf(u0.z, pB.z, aB0); aB0 = fmaf(u0.w, pB.w, aB0);
        aB1 = fmaf(u1.x, pB.x, aB1); aB1 = fmaf(u1.y, pB.y, aB1);
        aB1 = fmaf(u1.z, pB.z, aB1); aB1 = fmaf(u1.w, pB.w, aB1);
    }
    float bb0 = b1p[j0],   w20 = W2[j0];
    float bb1 = has1 ? b1p[j1] : 0.f;
    float w21 = has1 ? W2[j1]  : 0.f;
    float sA = fmaxf(aA0 + bb0, 0.f) * w20;
    float sB = fmaxf(aB0 + bb0, 0.f) * w20;
    if (has1) {
        sA = fmaf(fmaxf(aA1 + bb1, 0.f), w21, sA);
        sB = fmaf(fmaxf(aB1 + bb1, 0.f), w21, sB);
    }
    sA = wave_sum63(sA);
    sB = wave_sum63(sB);
    if (lane == 63) {
        float bias2 = b2[0];
        out[bA] = sA + bias2;
        out[bB] = sB + bias2;
    }
}

extern "C" void kernel_launch(void* const* d_in, const int* in_sizes, int n_in,
                              void* d_out, int out_size, void* d_ws, size_t ws_size,
                              hipStream_t stream) {
    (void)in_sizes; (void)n_in; (void)d_ws; (void)ws_size; (void)out_size;
    const float* x    = (const float*)d_in[0];
    const float* Wih0 = (const float*)d_in[1];
    const float* Whh0 = (const float*)d_in[2];
    const float* bih0 = (const float*)d_in[3];
    const float* bhh0 = (const float*)d_in[4];
    const float* Whr0 = (const float*)d_in[5];
    const float* Wih1 = (const float*)d_in[6];
    const float* Whh1 = (const float*)d_in[7];
    const float* bih1 = (const float*)d_in[8];
    const float* bhh1 = (const float*)d_in[9];
    const float* Whr1 = (const float*)d_in[10];
    const float* W1   = (const float*)d_in[11];
    const float* b1   = (const float*)d_in[12];
    const float* W2   = (const float*)d_in[13];
    const float* b2   = (const float*)d_in[14];
    float* outp = (float*)d_out;

    dim3 grid(16384 / (WAVES * BPW)), block(64 * WAVES);
    voltage_lstm_kernel<<<grid, block, 0, stream>>>(
        x, Wih0, Whh0, bih0, bhh0, Whr0,
        Wih1, Whh1, bih1, bhh1, Whr1,
        W1, b1, W2, b2, outp);
}